// Round 13
// baseline (191.642 us; speedup 1.0000x reference)
//
#include <hip/hip_runtime.h>
#include <math.h>

using u16 = unsigned short;
typedef __attribute__((ext_vector_type(8))) __bf16 bf16x8;
typedef __attribute__((ext_vector_type(4))) float f32x4;
typedef __attribute__((ext_vector_type(4))) float f4v;
typedef __attribute__((ext_vector_type(8))) u16 u16x8;

__device__ __forceinline__ u16 f2bf(float f) {
  unsigned u = __float_as_uint(f);
  u += 0x7fffu + ((u >> 16) & 1u);   // round-to-nearest-even
  return (u16)(u >> 16);
}
__device__ __forceinline__ float bf2f(u16 b) {
  unsigned u = ((unsigned)b) << 16;
  return __uint_as_float(u);
}

__device__ __forceinline__ void gload16(const void* g, void* l) {
  __builtin_amdgcn_global_load_lds(
      (const __attribute__((address_space(1))) unsigned int*)g,
      (__attribute__((address_space(3))) unsigned int*)l, 16, 0, 0);
}

__device__ __forceinline__ f32x4 MF(bf16x8 a, bf16x8 b, f32x4 c) {
  return __builtin_amdgcn_mfma_f32_16x16x32_bf16(a, b, c, 0, 0, 0);
}

// exp each bf16 element (f32 math), repack to bf16
__device__ __forceinline__ bf16x8 expb(bf16x8 a) {
  bf16x8 r;
  #pragma unroll
  for (int j = 0; j < 8; ++j) r[j] = (__bf16)__expf((float)a[j]);
  return r;
}

// ---------------------------------------------------------------- cast f32->bf16 (3 tensors)
__global__ __launch_bounds__(256) void cast3_f32_bf16(
    const float* __restrict__ p0, const float* __restrict__ p1,
    const float* __restrict__ p2, u16* __restrict__ out, size_t ostride) {
  int z = blockIdx.z;
  const float* in = (z == 0) ? p0 : (z == 1) ? p1 : p2;
  size_t i = ((size_t)blockIdx.x * 256 + threadIdx.x) * 8;
  f4v a = *reinterpret_cast<const f4v*>(in + i);
  f4v b = *reinterpret_cast<const f4v*>(in + i + 4);
  u16x8 r;
  r[0] = f2bf(a[0]); r[1] = f2bf(a[1]); r[2] = f2bf(a[2]); r[3] = f2bf(a[3]);
  r[4] = f2bf(b[0]); r[5] = f2bf(b[1]); r[6] = f2bf(b[2]); r[7] = f2bf(b[3]);
  *reinterpret_cast<u16x8*>(out + z * ostride + i) = r;
}

// ---------------------------------------------------------------- weight prep + l zero
// z=0: Wk->WkT; z=1: Wq->WqT (transpose-cast); z=2: Wv cast; z=3: zero l[8192].
__global__ __launch_bounds__(256) void wprep(
    const float* __restrict__ Wk, const float* __restrict__ Wq,
    const float* __restrict__ Wv, u16* __restrict__ wkT,
    u16* __restrict__ wqT, u16* __restrict__ wv_bf, float* __restrict__ lbuf) {
  int z = blockIdx.z;
  if (z < 2) {
    __shared__ float t[64][65];
    const float* I = z ? Wq : Wk;
    u16* O = z ? wqT : wkT;
    int c0 = blockIdx.x * 64, r0 = blockIdx.y * 64;
    int tx = threadIdx.x & 63, ty = threadIdx.x >> 6;
    #pragma unroll
    for (int i = 0; i < 64; i += 4)
      t[ty + i][tx] = I[(size_t)(r0 + ty + i) * 1024 + c0 + tx];
    __syncthreads();
    #pragma unroll
    for (int i = 0; i < 64; i += 4)
      O[(size_t)(c0 + ty + i) * 1024 + r0 + tx] = f2bf(t[tx][ty + i]);
  } else if (z == 2) {
    int b = blockIdx.y * 16 + blockIdx.x;           // 0..255
    size_t i = (size_t)b * 4096 + threadIdx.x * 16;
    #pragma unroll
    for (int h = 0; h < 2; ++h) {
      f4v a = *reinterpret_cast<const f4v*>(Wv + i + h * 8);
      f4v c = *reinterpret_cast<const f4v*>(Wv + i + h * 8 + 4);
      u16x8 r;
      r[0] = f2bf(a[0]); r[1] = f2bf(a[1]); r[2] = f2bf(a[2]); r[3] = f2bf(a[3]);
      r[4] = f2bf(c[0]); r[5] = f2bf(c[1]); r[6] = f2bf(c[2]); r[7] = f2bf(c[3]);
      *reinterpret_cast<u16x8*>(wv_bf + i + h * 8) = r;
    }
  } else {
    if (blockIdx.y) return;
    int i = blockIdx.x * 512 + threadIdx.x * 2;
    if (i < 8192) { lbuf[i] = 0.f; lbuf[i + 1] = 0.f; }
  }
}

// ================================================================ 8-wave 128x128 GEMM
// 2-phase dbuf, 512 threads = 8 waves (2M x 4N; wave out 64x32, acc[4][2]).
// MODE 0: plain (grid (M/128)*8) — used for Mt.
// MODE 1: causal QK^T, tri-packed, XCD-swizzled, bf16 out + per-row Σexp(s)
//         atomicAdd into lbuf (diag tiles write -100 to masked cols).
// MODE 2: causal PV on RAW scores: A-fragments exp'd in-register; epilogue
//         scales by 1/l[row]. K clipped to (bm+1)*128, longest-first, f32 out.
// MODE 3: stacked 2-way projection (Xq->Yq via Mt, Xv->Vt via Wv); V slab
//         retransposes its tile through LDS and writes Vt[e][t] directly.
template<typename OutT, int MODE>
__global__ __launch_bounds__(512) void gemm_bt8(
    const u16* __restrict__ A, const u16* __restrict__ B, OutT* __restrict__ C,
    int K, int lda, int ldb, int ldc,
    size_t sA, size_t sB, size_t sC, float alpha,
    OutT* __restrict__ C1, float* __restrict__ lbuf) {
  int bn, bm, bz = 0;
  int kEnd = K;
  bool whichV = false;
  const u16 *Ag, *Bg;
  OutT* Cg;
  if (MODE == 0) {
    bm = blockIdx.x >> 3;
    bn = blockIdx.x & 7;
    Ag = A + (size_t)bm * 128 * lda;
    Bg = B + (size_t)bn * 128 * ldb;
    Cg = C;
  } else if (MODE == 1) {                // grid 544 = 4 * 136 lower-tri tiles
    int h = blockIdx.x;
    int l = (h & 7) * 68 + (h >> 3);
    bz = l / 136;
    int t = l % 136;
    bm = (int)((sqrtf(8.f * (float)t + 1.f) - 1.f) * 0.5f);
    while ((bm + 1) * (bm + 2) / 2 <= t) ++bm;
    while (bm * (bm + 1) / 2 > t) --bm;
    bn = t - bm * (bm + 1) / 2;
    Ag = A + sA * bz + (size_t)bm * 128 * lda;
    Bg = B + sB * bz + (size_t)bn * 128 * ldb;
    Cg = C + sC * bz;
  } else if (MODE == 2) {                // grid 512
    int l = blockIdx.x;
    bm = 15 - (l >> 5);                  // longest kEnd first
    int rest = l & 31;
    bz = rest >> 3;
    bn = rest & 7;
    kEnd = (K < (bm + 1) * 128) ? K : (bm + 1) * 128;
    Ag = A + sA * bz + (size_t)bm * 128 * lda;
    Bg = B + sB * bz + (size_t)bn * 128 * ldb;
    Cg = C + sC * bz;
  } else {                               // MODE 3, grid 1024, XCD-chunked
    int h = blockIdx.x;
    int l = (h & 7) * 128 + (h >> 3);
    bn = l & 7;
    int bm128 = l >> 3;
    whichV = (bm128 >> 6) != 0;
    bm = bm128 & 63;
    Ag = A + (size_t)bm128 * 128 * lda;
    Bg = B + (whichV ? sB : 0) + (size_t)bn * 128 * ldb;
    Cg = C;                              // used only for the Yq slab
  }

  // LDS: staging (2x8KB A + 2x8KB B = 32KB); reused post-loop as transpose
  // tile (V slab, 33,024B) or as the [4][128] f32 row-sum combine (MODE 1).
  __shared__ __align__(16) char smem[33024];
  u16* AsB = (u16*)smem;            // [2][4096]
  u16* BsB = AsB + 8192;            // [2][4096]

  const int tid = threadIdx.x;
  const int lane = tid & 63, wv = tid >> 6;   // 8 waves
  const int wr = wv >> 2, wc = wv & 3;        // 2M x 4N
  const int fr = lane & 15, kq = (lane >> 4) * 8;
  const int g4 = (lane >> 4) * 4;

  // staging: wave wv owns A-chunk wv + B-chunk wv (1KB each)
  const int e0 = wv * 512 + lane * 8;
  const int r0 = e0 >> 5, c0 = e0 & 31;
  const u16* a0 = Ag + (size_t)r0 * lda + c0;
  const u16* b0 = Bg + (size_t)r0 * ldb + c0;

  f32x4 acc[4][2] = {};
  const int nt = kEnd / 32;

  gload16(a0, &AsB[wv * 512]);
  gload16(b0, &BsB[wv * 512]);
  __syncthreads();

  for (int t = 0; t < nt; ++t) {
    const int cur = t & 1;
    if (t + 1 < nt) {
      const int k0 = (t + 1) * 32;
      gload16(a0 + k0, &AsB[(cur ^ 1) * 4096 + wv * 512]);
      gload16(b0 + k0, &BsB[(cur ^ 1) * 4096 + wv * 512]);
    }
    const u16* Ac = AsB + cur * 4096;
    const u16* Bc = BsB + cur * 4096;
    bf16x8 af[4], bfv[2];
    #pragma unroll
    for (int m = 0; m < 4; ++m) {
      af[m] = *reinterpret_cast<const bf16x8*>(&Ac[(wr * 64 + m * 16 + fr) * 32 + kq]);
      if constexpr (MODE == 2) af[m] = expb(af[m]);   // P = exp(S), unnormalized
    }
    #pragma unroll
    for (int n = 0; n < 2; ++n)
      bfv[n] = *reinterpret_cast<const bf16x8*>(&Bc[(wc * 32 + n * 16 + fr) * 32 + kq]);
    #pragma unroll
    for (int m = 0; m < 4; ++m)
      #pragma unroll
      for (int n = 0; n < 2; ++n)
        acc[m][n] = MF(af[m], bfv[n], acc[m][n]);
    __syncthreads();
  }

  if constexpr (MODE == 1) {
    // store bf16 scores (diag-masked) + per-row sum of exp -> lbuf atomics
    float psum[4][4];
    #pragma unroll
    for (int m = 0; m < 4; ++m)
      #pragma unroll
      for (int j = 0; j < 4; ++j) {
        int tr = wr * 64 + g4 + m * 16 + j;
        float rs = 0.f;
        #pragma unroll
        for (int n = 0; n < 2; ++n) {
          float val = acc[m][n][j] * alpha;
          int tc = wc * 32 + fr + n * 16;
          if (bm == bn && tc > tr) val = -100.f;
          Cg[(size_t)(bm * 128 + tr) * ldc + (bn * 128 + tc)] = f2bf(val);
          rs += __expf(val);
        }
        psum[m][j] = rs;
      }
    #pragma unroll
    for (int o = 1; o < 16; o <<= 1)
      #pragma unroll
      for (int m = 0; m < 4; ++m)
        #pragma unroll
        for (int j = 0; j < 4; ++j)
          psum[m][j] += __shfl_xor(psum[m][j], o, 64);
    float* lsum = (float*)smem;        // [4 wc][128 rows]
    if (fr == 0)
      #pragma unroll
      for (int m = 0; m < 4; ++m)
        #pragma unroll
        for (int j = 0; j < 4; ++j)
          lsum[wc * 128 + wr * 64 + g4 + m * 16 + j] = psum[m][j];
    __syncthreads();
    if (tid < 128) {
      float s = lsum[tid] + lsum[128 + tid] + lsum[256 + tid] + lsum[384 + tid];
      atomicAdd(&lbuf[(size_t)bz * 2048 + bm * 128 + tid], s);
    }
    return;
  }

  if constexpr (MODE == 3) {
    if (whichV) {
      // retranspose 128x128 tile through LDS, write Vt[e][t] coalesced.
      u16* tt = (u16*)smem;
      #pragma unroll
      for (int m = 0; m < 4; ++m)
        #pragma unroll
        for (int n = 0; n < 2; ++n)
          #pragma unroll
          for (int j = 0; j < 4; ++j)
            tt[(wr * 64 + g4 + m * 16 + j) * 129 +
               (wc * 32 + fr + n * 16)] = f2bf(acc[m][n][j]);
      __syncthreads();
      const int orow = tid >> 2, oc = (tid & 3) * 32;
      size_t base = (size_t)(bm >> 4) * (1024 * 2048) +
                    (size_t)(bn * 128 + orow) * 2048 +
                    (size_t)(bm & 15) * 128 + oc;
      #pragma unroll
      for (int jj = 0; jj < 4; ++jj) {
        u16x8 o;
        #pragma unroll
        for (int j = 0; j < 8; ++j) o[j] = tt[(oc + jj * 8 + j) * 129 + orow];
        *reinterpret_cast<u16x8*>(&C1[base + jj * 8]) = o;
      }
      return;
    }
  }

  float il[4][4];
  if constexpr (MODE == 2) {
    #pragma unroll
    for (int m = 0; m < 4; ++m)
      #pragma unroll
      for (int j = 0; j < 4; ++j)
        il[m][j] = 1.0f / lbuf[(size_t)bz * 2048 + bm * 128 + wr * 64 + g4 + m * 16 + j];
  }

  const int row0 = bm * 128 + wr * 64 + g4;
  const int col0 = bn * 128 + wc * 32 + fr;
  #pragma unroll
  for (int m = 0; m < 4; ++m)
    #pragma unroll
    for (int n = 0; n < 2; ++n) {
      #pragma unroll
      for (int j = 0; j < 4; ++j) {
        float val = acc[m][n][j] * alpha;
        if constexpr (MODE == 2) val = acc[m][n][j] * il[m][j];
        size_t idx = (size_t)(row0 + m * 16 + j) * ldc + (col0 + n * 16);
        if constexpr (sizeof(OutT) == 2) Cg[idx] = f2bf(val);
        else Cg[idx] = val;
      }
    }
}

// ---------------------------------------------------------------- launcher
extern "C" void kernel_launch(void* const* d_in, const int* in_sizes, int n_in,
                              void* d_out, int out_size, void* d_ws, size_t ws_size,
                              hipStream_t stream) {
  const float* q  = (const float*)d_in[0];
  const float* k  = (const float*)d_in[1];
  const float* v  = (const float*)d_in[2];
  // d_in[3] = attn_mask (causal tril) — handled analytically
  const float* Wq = (const float*)d_in[4];
  const float* Wk = (const float*)d_in[5];
  const float* Wv = (const float*)d_in[6];
  float* out = (float*)d_out;
  char* ws = (char*)d_ws;

  const size_t MB = 1024ull * 1024ull;
  // W-merge: S = Xq.(Wq^T.Wk).Xk^T — K-projection replaced by the Xk cast.
  // Softmax-free: QK accumulates l[r]=Σexp(s) via atomics; PV exps fragments
  // and scales by 1/l. sc (32MB) overlays qb slabs 0,1 (dead after proj).
  u16* sc   = (u16*)ws;               // 0..32MB  bf16 scores [4][2048][2048]
  u16* qb   = (u16*)ws;               // slabs: 0=Xq, 1=Xv (16MB each)
  u16* xk   = (u16*)(ws + 32 * MB);   // Xk bf16 (16MB, lives through QK)
  u16* wsl  = (u16*)(ws + 48 * MB);   // 4MB: slab0 = Mt, slab1 = Wv_bf
  u16* wkT  = (u16*)(ws + 52 * MB);   // 2MB (dead after Mt)
  u16* wqT  = (u16*)(ws + 54 * MB);   // 2MB (dead after Mt)
  u16* Vt   = (u16*)(ws + 56 * MB);   // 16MB (written by proj, read by PV)
  u16* Yq   = (u16*)(ws + 72 * MB);   // 16MB
  float* lb = (float*)(ws + 88 * MB); // 32KB row sums [4][2048] -> peak 88MB+
  (void)in_sizes; (void)n_in; (void)out_size; (void)ws_size;

  // 1. weight prep + l zero (one dispatch)
  wprep<<<dim3(16, 16, 4), 256, 0, stream>>>(Wk, Wq, Wv, wkT, wqT,
                                             wsl + 1048576, lb);

  // 2. Mt = WkT . WqT^T = Wk^T.Wq  (Yq = Xq.Mt^T = Xq.Wq^T.Wk)
  gemm_bt8<u16, 0><<<64, 512, 0, stream>>>(
      wkT, wqT, wsl, 1024, 1024, 1024, 1024, 0, 0, 0, 1.0f, nullptr, nullptr);

  // 3. big cast: z0=Xq, z1=Xv, z2=Xk
  cast3_f32_bf16<<<dim3(4096, 1, 3), 256, 0, stream>>>(q, v, k, qb, 8ull * MB);

  // 4. 2-slab projection (1024 blocks): Yq = Xq.Mt^T; Vt = (Xv.Wv^T)^T in-epilogue
  gemm_bt8<u16, 3><<<1024, 512, 0, stream>>>(
      qb, wsl, Yq, 1024, 1024, 1024, 1024,
      0, 1048576, 0, 1.0f, Vt, nullptr);

  // 5. S = Yq . Xk^T (scaled, tri-packed) -> bf16 scores + row exp-sums
  gemm_bt8<u16, 1><<<544, 512, 0, stream>>>(
      Yq, xk, sc, 1024, 1024, 1024, 2048,
      (size_t)2048 * 1024, (size_t)2048 * 1024, (size_t)2048 * 2048, 0.03125f,
      nullptr, lb);

  // 6. PV: exp(S) . Vt^T scaled by 1/l -> out f32, longest-first
  gemm_bt8<float, 2><<<512, 512, 0, stream>>>(
      sc, Vt, out, 2048, 2048, 2048, 1024,
      (size_t)2048 * 2048, (size_t)1024 * 2048, (size_t)2048 * 1024, 1.0f,
      nullptr, lb);
}

// Round 14
// 171.628 us; speedup vs baseline: 1.1166x; 1.1166x over previous
//
#include <hip/hip_runtime.h>
#include <math.h>

using u16 = unsigned short;
typedef __attribute__((ext_vector_type(8))) __bf16 bf16x8;
typedef __attribute__((ext_vector_type(4))) float f32x4;
typedef __attribute__((ext_vector_type(4))) float f4v;
typedef __attribute__((ext_vector_type(8))) u16 u16x8;

__device__ __forceinline__ u16 f2bf(float f) {
  unsigned u = __float_as_uint(f);
  u += 0x7fffu + ((u >> 16) & 1u);   // round-to-nearest-even
  return (u16)(u >> 16);
}
__device__ __forceinline__ float bf2f(u16 b) {
  unsigned u = ((unsigned)b) << 16;
  return __uint_as_float(u);
}

__device__ __forceinline__ void gload16(const void* g, void* l) {
  __builtin_amdgcn_global_load_lds(
      (const __attribute__((address_space(1))) unsigned int*)g,
      (__attribute__((address_space(3))) unsigned int*)l, 16, 0, 0);
}

__device__ __forceinline__ f32x4 MF(bf16x8 a, bf16x8 b, f32x4 c) {
  return __builtin_amdgcn_mfma_f32_16x16x32_bf16(a, b, c, 0, 0, 0);
}

// ---------------------------------------------------------------- cast f32->bf16 (3 tensors)
__global__ __launch_bounds__(256) void cast3_f32_bf16(
    const float* __restrict__ p0, const float* __restrict__ p1,
    const float* __restrict__ p2, u16* __restrict__ out, size_t ostride) {
  int z = blockIdx.z;
  const float* in = (z == 0) ? p0 : (z == 1) ? p1 : p2;
  size_t i = ((size_t)blockIdx.x * 256 + threadIdx.x) * 8;
  f4v a = *reinterpret_cast<const f4v*>(in + i);
  f4v b = *reinterpret_cast<const f4v*>(in + i + 4);
  u16x8 r;
  r[0] = f2bf(a[0]); r[1] = f2bf(a[1]); r[2] = f2bf(a[2]); r[3] = f2bf(a[3]);
  r[4] = f2bf(b[0]); r[5] = f2bf(b[1]); r[6] = f2bf(b[2]); r[7] = f2bf(b[3]);
  *reinterpret_cast<u16x8*>(out + z * ostride + i) = r;
}

// ---------------------------------------------------------------- all weight prep, one dispatch
// z=0: Wk -> WkT (transpose-cast); z=1: Wq -> WqT; z=2: Wv -> wv_bf (plain cast).
__global__ __launch_bounds__(256) void wprep(
    const float* __restrict__ Wk, const float* __restrict__ Wq,
    const float* __restrict__ Wv, u16* __restrict__ wkT,
    u16* __restrict__ wqT, u16* __restrict__ wv_bf) {
  int z = blockIdx.z;
  if (z < 2) {
    __shared__ float t[64][65];
    const float* I = z ? Wq : Wk;
    u16* O = z ? wqT : wkT;
    int c0 = blockIdx.x * 64, r0 = blockIdx.y * 64;
    int tx = threadIdx.x & 63, ty = threadIdx.x >> 6;
    #pragma unroll
    for (int i = 0; i < 64; i += 4)
      t[ty + i][tx] = I[(size_t)(r0 + ty + i) * 1024 + c0 + tx];
    __syncthreads();
    #pragma unroll
    for (int i = 0; i < 64; i += 4)
      O[(size_t)(c0 + ty + i) * 1024 + r0 + tx] = f2bf(t[tx][ty + i]);
  } else {
    int b = blockIdx.y * 16 + blockIdx.x;           // 0..255
    size_t i = (size_t)b * 4096 + threadIdx.x * 16;
    #pragma unroll
    for (int h = 0; h < 2; ++h) {
      f4v a = *reinterpret_cast<const f4v*>(Wv + i + h * 8);
      f4v c = *reinterpret_cast<const f4v*>(Wv + i + h * 8 + 4);
      u16x8 r;
      r[0] = f2bf(a[0]); r[1] = f2bf(a[1]); r[2] = f2bf(a[2]); r[3] = f2bf(a[3]);
      r[4] = f2bf(c[0]); r[5] = f2bf(c[1]); r[6] = f2bf(c[2]); r[7] = f2bf(c[3]);
      *reinterpret_cast<u16x8*>(wv_bf + i + h * 8) = r;
    }
  }
}

// ================================================================ 8-wave 128x128 GEMM
// 2-phase dbuf, 512 threads = 8 waves (2M x 4N; wave out 64x32, acc[4][2],
// 8 MFMA/iter). Staging: wave w owns A-chunk w + B-chunk w (1KB each).
// MODE 0: plain (grid (M/128)*8) — used for Mt.
// MODE 1: causal QK^T, tri-packed, XCD-swizzled, bf16 out (alpha pre-scale).
// MODE 2: causal PV, K clipped to (bm+1)*128, longest-first, f32 out.
// MODE 3: stacked 2-way projection. Yq slab: Xq.Mt^T standard. V slab: operands
//         SWAPPED (A=Wv tile, B=Xv tile) so the MFMA directly produces
//         D = Wv.Xv^T = (Xv.Wv^T)^T = Vt[e][t] — free transpose, no LDS pass.
template<typename OutT, int MODE>
__global__ __launch_bounds__(512) void gemm_bt8(
    const u16* __restrict__ A, const u16* __restrict__ B, OutT* __restrict__ C,
    int K, int lda, int ldb, int ldc,
    size_t sA, size_t sB, size_t sC, float alpha,
    OutT* __restrict__ C1) {
  int bn, bm, bz = 0;
  int kEnd = K;
  bool whichV = false;
  const u16 *Ag, *Bg;
  OutT* Cg;
  if (MODE == 0) {
    bm = blockIdx.x >> 3;
    bn = blockIdx.x & 7;
    Ag = A + (size_t)bm * 128 * lda;
    Bg = B + (size_t)bn * 128 * ldb;
    Cg = C;
  } else if (MODE == 1) {                // grid 544 = 4 * 136 lower-tri tiles
    int h = blockIdx.x;
    int l = (h & 7) * 68 + (h >> 3);
    bz = l / 136;
    int t = l % 136;
    bm = (int)((sqrtf(8.f * (float)t + 1.f) - 1.f) * 0.5f);
    while ((bm + 1) * (bm + 2) / 2 <= t) ++bm;
    while (bm * (bm + 1) / 2 > t) --bm;
    bn = t - bm * (bm + 1) / 2;
    Ag = A + sA * bz + (size_t)bm * 128 * lda;
    Bg = B + sB * bz + (size_t)bn * 128 * ldb;
    Cg = C + sC * bz;
  } else if (MODE == 2) {                // grid 512
    int l = blockIdx.x;
    bm = 15 - (l >> 5);                  // longest kEnd first
    int rest = l & 31;
    bz = rest >> 3;
    bn = rest & 7;
    kEnd = (K < (bm + 1) * 128) ? K : (bm + 1) * 128;
    Ag = A + sA * bz + (size_t)bm * 128 * lda;
    Bg = B + sB * bz + (size_t)bn * 128 * ldb;
    Cg = C + sC * bz;
  } else {                               // MODE 3, grid 1024, XCD-chunked
    int h = blockIdx.x;
    int l = (h & 7) * 128 + (h >> 3);
    bn = l & 7;
    int bm128 = l >> 3;
    whichV = (bm128 >> 6) != 0;
    bm = bm128 & 63;
    if (whichV) {                        // swapped: A=Wv tile, B=Xv tile
      Ag = B + sB + (size_t)bn * 128 * ldb;
      Bg = A + (size_t)bm128 * 128 * lda;
    } else {
      Ag = A + (size_t)bm128 * 128 * lda;
      Bg = B + (size_t)bn * 128 * ldb;
    }
    Cg = C;                              // used only for the Yq slab
  }

  __shared__ __align__(16) u16 As[2][128 * 32];
  __shared__ __align__(16) u16 Bs[2][128 * 32];

  const int tid = threadIdx.x;
  const int lane = tid & 63, wv = tid >> 6;   // 8 waves
  const int wr = wv >> 2, wc = wv & 3;        // 2M x 4N
  const int fr = lane & 15, kq = (lane >> 4) * 8;
  const int g4 = (lane >> 4) * 4;

  // staging: wave wv owns A-chunk wv + B-chunk wv (1KB each)
  const int e0 = wv * 512 + lane * 8;
  const int r0 = e0 >> 5, c0 = e0 & 31;
  const u16* a0 = Ag + (size_t)r0 * lda + c0;
  const u16* b0 = Bg + (size_t)r0 * ldb + c0;

  f32x4 acc[4][2] = {};
  const int nt = kEnd / 32;

  gload16(a0, &As[0][wv * 512]);
  gload16(b0, &Bs[0][wv * 512]);
  __syncthreads();

  for (int t = 0; t < nt; ++t) {
    const int cur = t & 1;
    if (t + 1 < nt) {
      const int k0 = (t + 1) * 32;
      gload16(a0 + k0, &As[cur ^ 1][wv * 512]);
      gload16(b0 + k0, &Bs[cur ^ 1][wv * 512]);
    }
    bf16x8 af[4], bfv[2];
    #pragma unroll
    for (int m = 0; m < 4; ++m)
      af[m] = *reinterpret_cast<const bf16x8*>(&As[cur][(wr * 64 + m * 16 + fr) * 32 + kq]);
    #pragma unroll
    for (int n = 0; n < 2; ++n)
      bfv[n] = *reinterpret_cast<const bf16x8*>(&Bs[cur][(wc * 32 + n * 16 + fr) * 32 + kq]);
    #pragma unroll
    for (int m = 0; m < 4; ++m)
      #pragma unroll
      for (int n = 0; n < 2; ++n)
        acc[m][n] = MF(af[m], bfv[n], acc[m][n]);
    __syncthreads();
  }

  if constexpr (MODE == 3) {
    if (whichV) {
      // acc[m][n] = Wv-tile . Xv-tile^T fragment: row (m-dim) = e, col (n-dim) = t.
      // e = bn*128 + wr*64 + m*16 + g4 + j;  t_stacked = bm*128 + wc*32 + n*16 + fr.
      const int eb = bn * 128 + wr * 64 + g4;
      const int tb = (bm & 15) * 128 + wc * 32 + fr;
      const size_t zoff = (size_t)(bm >> 4) * (1024 * 2048);
      #pragma unroll
      for (int m = 0; m < 4; ++m)
        #pragma unroll
        for (int n = 0; n < 2; ++n)
          #pragma unroll
          for (int j = 0; j < 4; ++j)
            C1[zoff + (size_t)(eb + m * 16 + j) * 2048 + (tb + n * 16)] =
                f2bf(acc[m][n][j]);
      return;
    }
  }

  const int row0 = bm * 128 + wr * 64 + g4;
  const int col0 = bn * 128 + wc * 32 + fr;
  #pragma unroll
  for (int m = 0; m < 4; ++m)
    #pragma unroll
    for (int n = 0; n < 2; ++n) {
      #pragma unroll
      for (int j = 0; j < 4; ++j) {
        float val = acc[m][n][j] * alpha;
        size_t idx = (size_t)(row0 + m * 16 + j) * ldc + (col0 + n * 16);
        if constexpr (sizeof(OutT) == 2) Cg[idx] = f2bf(val);
        else Cg[idx] = val;
      }
    }
}

// ---------------------------------------------------------------- causal softmax (bf16 in/out, in-place)
__global__ __launch_bounds__(256) void softmax_causal(u16* __restrict__ sc) {
  int r = blockIdx.x;          // 0..8191
  int s = r & 2047;
  u16* row = sc + (size_t)r * 2048;
  int tid = threadIdx.x;
  int t0 = tid * 8;
  u16x8 raw = {0, 0, 0, 0, 0, 0, 0, 0};
  if (t0 <= s) raw = *reinterpret_cast<const u16x8*>(row + t0);
  float v[8];
  float mx = -1e30f;
  #pragma unroll
  for (int j = 0; j < 8; ++j) {
    v[j] = ((t0 + j) <= s) ? bf2f(raw[j]) : -1e30f;
    mx = fmaxf(mx, v[j]);
  }
  #pragma unroll
  for (int o = 32; o; o >>= 1) mx = fmaxf(mx, __shfl_xor(mx, o, 64));
  __shared__ float red[8];
  if ((tid & 63) == 0) red[tid >> 6] = mx;
  __syncthreads();
  mx = fmaxf(fmaxf(red[0], red[1]), fmaxf(red[2], red[3]));
  float p[8];
  float sum = 0.f;
  #pragma unroll
  for (int j = 0; j < 8; ++j) {
    p[j] = ((t0 + j) <= s) ? __expf(v[j] - mx) : 0.f;
    sum += p[j];
  }
  #pragma unroll
  for (int o = 32; o; o >>= 1) sum += __shfl_xor(sum, o, 64);
  if ((tid & 63) == 0) red[4 + (tid >> 6)] = sum;
  __syncthreads();
  sum = red[4] + red[5] + red[6] + red[7];
  float inv = 1.0f / sum;
  u16x8 o8;
  #pragma unroll
  for (int j = 0; j < 8; ++j) o8[j] = f2bf(p[j] * inv);
  if (t0 <= (s | 127))   // PV reads cols < (bm+1)*128 only
    *reinterpret_cast<u16x8*>(row + t0) = o8;
}

// ---------------------------------------------------------------- launcher
extern "C" void kernel_launch(void* const* d_in, const int* in_sizes, int n_in,
                              void* d_out, int out_size, void* d_ws, size_t ws_size,
                              hipStream_t stream) {
  const float* q  = (const float*)d_in[0];
  const float* k  = (const float*)d_in[1];
  const float* v  = (const float*)d_in[2];
  // d_in[3] = attn_mask (causal tril) — handled analytically
  const float* Wq = (const float*)d_in[4];
  const float* Wk = (const float*)d_in[5];
  const float* Wv = (const float*)d_in[6];
  float* out = (float*)d_out;
  char* ws = (char*)d_ws;

  const size_t MB = 1024ull * 1024ull;
  // W-merge: S = Xq.(Wq^T.Wk).Xk^T — K-projection replaced by the Xk cast.
  // sc (32MB) overlays qb slabs 0,1 (Xq,Xv — dead after proj). xk lives
  // through QK. wkT/wqT dead after Mt; wsl dead after proj. No Vp:
  // proj's V slab writes Vt directly via swapped-operand MFMA.
  u16* sc   = (u16*)ws;               // 0..32MB  bf16 scores [4][2048][2048]
  u16* qb   = (u16*)ws;               // slabs: 0=Xq, 1=Xv (16MB each)
  u16* xk   = (u16*)(ws + 32 * MB);   // Xk bf16 (16MB, lives through QK)
  u16* wsl  = (u16*)(ws + 48 * MB);   // 4MB: slab0 = Mt, slab1 = Wv_bf
  u16* wkT  = (u16*)(ws + 52 * MB);   // 2MB (dead after Mt)
  u16* wqT  = (u16*)(ws + 54 * MB);   // 2MB (dead after Mt)
  u16* Vt   = (u16*)(ws + 56 * MB);   // 16MB (written by proj, read by PV)
  u16* Yq   = (u16*)(ws + 72 * MB);   // 16MB  -> peak 88MB
  (void)in_sizes; (void)n_in; (void)out_size; (void)ws_size;

  // 1. weight prep (one dispatch): WkT, WqT transpose-casts + Wv cast
  wprep<<<dim3(16, 16, 3), 256, 0, stream>>>(Wk, Wq, Wv, wkT, wqT,
                                             wsl + 1048576);

  // 2. Mt = WkT . WqT^T = Wk^T.Wq  (Yq = Xq.Mt^T = Xq.Wq^T.Wk)
  gemm_bt8<u16, 0><<<64, 512, 0, stream>>>(
      wkT, wqT, wsl, 1024, 1024, 1024, 1024, 0, 0, 0, 1.0f, nullptr);

  // 3. big cast: z0=Xq, z1=Xv, z2=Xk
  cast3_f32_bf16<<<dim3(4096, 1, 3), 256, 0, stream>>>(q, v, k, qb, 8ull * MB);

  // 4. 2-slab projection (1024 blocks): Yq = Xq.Mt^T; Vt = Wv.Xv^T (swapped)
  gemm_bt8<u16, 3><<<1024, 512, 0, stream>>>(
      qb, wsl, Yq, 1024, 1024, 1024, 1024,
      0, 1048576, 0, 1.0f, Vt);

  // 5. S = Yq . Xk^T (scaled, tri-packed, XCD-swizzled) -> bf16 scores
  gemm_bt8<u16, 1><<<544, 512, 0, stream>>>(
      Yq, xk, sc, 1024, 1024, 1024, 2048,
      (size_t)2048 * 1024, (size_t)2048 * 1024, (size_t)2048 * 2048, 0.03125f,
      nullptr);

  // 6. causal softmax, bf16 in/out in place
  softmax_causal<<<8192, 256, 0, stream>>>(sc);

  // 7. PV: P[2048][2048] . Vt[1024][2048]^T -> out f32, longest-first
  gemm_bt8<float, 2><<<512, 512, 0, stream>>>(
      sc, Vt, out, 2048, 2048, 2048, 1024,
      (size_t)2048 * 2048, (size_t)1024 * 2048, (size_t)2048 * 1024, 1.0f,
      nullptr);
}

// Round 15
// 161.976 us; speedup vs baseline: 1.1831x; 1.0596x over previous
//
#include <hip/hip_runtime.h>
#include <math.h>

using u16 = unsigned short;
typedef __attribute__((ext_vector_type(8))) __bf16 bf16x8;
typedef __attribute__((ext_vector_type(4))) float f32x4;
typedef __attribute__((ext_vector_type(4))) float f4v;
typedef __attribute__((ext_vector_type(8))) u16 u16x8;

__device__ __forceinline__ u16 f2bf(float f) {
  unsigned u = __float_as_uint(f);
  u += 0x7fffu + ((u >> 16) & 1u);   // round-to-nearest-even
  return (u16)(u >> 16);
}
__device__ __forceinline__ float bf2f(u16 b) {
  unsigned u = ((unsigned)b) << 16;
  return __uint_as_float(u);
}

__device__ __forceinline__ void gload16(const void* g, void* l) {
  __builtin_amdgcn_global_load_lds(
      (const __attribute__((address_space(1))) unsigned int*)g,
      (__attribute__((address_space(3))) unsigned int*)l, 16, 0, 0);
}

__device__ __forceinline__ f32x4 MF(bf16x8 a, bf16x8 b, f32x4 c) {
  return __builtin_amdgcn_mfma_f32_16x16x32_bf16(a, b, c, 0, 0, 0);
}

#define BARX() __builtin_amdgcn_s_barrier()
#define LGKM0() asm volatile("s_waitcnt lgkmcnt(0)" ::: "memory")
#define VMW4() asm volatile("s_waitcnt vmcnt(4)" ::: "memory")
#define VMW0() asm volatile("s_waitcnt vmcnt(0)" ::: "memory")

// ---------------------------------------------------------------- unified prep (one dispatch)
// blocks [0,12288): cast q/v/k f32->bf16 into qb slabs 0/1/2.
// blocks [12288,12800): transpose-cast Wk->WkT (z=0), Wq->WqT (z=1).
// blocks [12800,13056): cast Wv -> wv_bf.
__global__ __launch_bounds__(256) void prep(
    const float* __restrict__ q, const float* __restrict__ v,
    const float* __restrict__ k, const float* __restrict__ Wk,
    const float* __restrict__ Wq, const float* __restrict__ Wv,
    u16* __restrict__ qb, u16* __restrict__ wkT, u16* __restrict__ wqT,
    u16* __restrict__ wv_bf) {
  __shared__ float t[64][65];
  int b = blockIdx.x;
  if (b < 12288) {
    int z = b >> 12;
    int bb = b & 4095;
    const float* in = (z == 0) ? q : (z == 1) ? v : k;
    size_t i = ((size_t)bb * 256 + threadIdx.x) * 8;
    f4v a = *reinterpret_cast<const f4v*>(in + i);
    f4v c = *reinterpret_cast<const f4v*>(in + i + 4);
    u16x8 r;
    r[0] = f2bf(a[0]); r[1] = f2bf(a[1]); r[2] = f2bf(a[2]); r[3] = f2bf(a[3]);
    r[4] = f2bf(c[0]); r[5] = f2bf(c[1]); r[6] = f2bf(c[2]); r[7] = f2bf(c[3]);
    *reinterpret_cast<u16x8*>(qb + (size_t)z * 8388608 + i) = r;
  } else if (b < 12800) {
    int c = b - 12288;
    int z = c >> 8, idx = c & 255;
    const float* I = z ? Wq : Wk;
    u16* O = z ? wqT : wkT;
    int c0 = (idx & 15) * 64, r0 = (idx >> 4) * 64;
    int tx = threadIdx.x & 63, ty = threadIdx.x >> 6;
    #pragma unroll
    for (int i = 0; i < 64; i += 4)
      t[ty + i][tx] = I[(size_t)(r0 + ty + i) * 1024 + c0 + tx];
    __syncthreads();
    #pragma unroll
    for (int i = 0; i < 64; i += 4)
      O[(size_t)(c0 + ty + i) * 1024 + r0 + tx] = f2bf(t[tx][ty + i]);
  } else {
    int bb = b - 12800;                 // 0..255
    size_t i = (size_t)bb * 4096 + threadIdx.x * 16;
    #pragma unroll
    for (int h = 0; h < 2; ++h) {
      f4v a = *reinterpret_cast<const f4v*>(Wv + i + h * 8);
      f4v c = *reinterpret_cast<const f4v*>(Wv + i + h * 8 + 4);
      u16x8 r;
      r[0] = f2bf(a[0]); r[1] = f2bf(a[1]); r[2] = f2bf(a[2]); r[3] = f2bf(a[3]);
      r[4] = f2bf(c[0]); r[5] = f2bf(c[1]); r[6] = f2bf(c[2]); r[7] = f2bf(c[3]);
      *reinterpret_cast<u16x8*>(wv_bf + i + h * 8) = r;
    }
  }
}

// ================================================================ 256x256 8-phase projection
// Grid 256 (= one full scheduling round at 1 block/CU), 512 threads = 8 waves
// (2M x 4N), per-wave C 128x64. K=1024 -> 16 K-tiles of 64. LDS 128KB dbuf.
// Tiles [0,128): Yq = Xq(8192x1024).Mt^T   (bm=li>>2 in 0..31, bn=li&3)
// Tiles [128,256): D = Wv(1024x1024).Xv^T = Vt rows (swapped-operand transpose)
//                  (bm=li&3 Wv row-tile, bn=li>>2 Xv stacked row-tile)
// XOR swizzle: 16B slot ^= (row&7), pre-swizzled global src + swizzled ds_read.
// Staging stream & counted vmcnt(4) identical to the R4-verified kernel.
__global__ __launch_bounds__(512, 1) void proj256(
    const u16* __restrict__ Xq, const u16* __restrict__ Xv,
    const u16* __restrict__ Mt, const u16* __restrict__ Wv,
    u16* __restrict__ Yq, u16* __restrict__ Vt) {
  int h = blockIdx.x;
  int l = (h & 7) * 32 + (h >> 3);     // bijective XCD chunking (256 % 8 == 0)
  const bool wV = l >= 128;
  int li = l & 127;
  int bm, bn;
  const u16 *Ag, *Bg;
  if (!wV) {
    bm = li >> 2; bn = li & 3;
    Ag = Xq + (size_t)bm * 256 * 1024;
    Bg = Mt + (size_t)bn * 256 * 1024;
  } else {
    bm = li & 3; bn = li >> 2;
    Ag = Wv + (size_t)bm * 256 * 1024;
    Bg = Xv + (size_t)bn * 256 * 1024;
  }

  __shared__ __align__(16) char sm[131072];

  const int tid = threadIdx.x;
  const int lane = tid & 63, wv = tid >> 6;
  const int wr = wv >> 2, wc = wv & 3;
  const int fr = lane & 15, hi = lane >> 4, fr7 = lane & 7;
  const int l3 = lane >> 3;
  const int colsw = ((lane & 7) ^ l3) * 8;
  const int lnx16 = lane * 16;

  const u16 *pA[2][2], *pB[2][2];
  int ldsA[2][2], ldsB[2][2];
  #pragma unroll
  for (int hh = 0; hh < 2; ++hh)
    #pragma unroll
    for (int j = 0; j < 2; ++j) {
      int row = hh * 128 + wv * 8 + j * 64 + l3;
      pA[hh][j] = Ag + (size_t)row * 1024 + colsw;
      pB[hh][j] = Bg + (size_t)row * 1024 + colsw;
      ldsA[hh][j] = hh * 16384 + (wv + j * 8) * 1024 + lnx16;
      ldsB[hh][j] = 32768 + ldsA[hh][j];
    }

  const int aBase = wr * 16384 + fr * 128;
  const int bBase = 32768 + (wc >> 1) * 16384 + ((wc & 1) * 64 + fr) * 128;
  const int sl0 = (hi ^ fr7) << 4;
  const int sl1 = ((4 + hi) ^ fr7) << 4;

#define RDA(buf, m, kk) (*(const bf16x8*)((buf) + aBase + (m) * 2048 + ((kk) ? sl1 : sl0)))
#define RDB(buf, n, kk) (*(const bf16x8*)((buf) + bBase + (n) * 2048 + ((kk) ? sl1 : sl0)))

  f32x4 acc[8][4] = {};
  const int nt = 16;

  {
    char* b0 = sm;
    gload16(pA[0][0], b0 + ldsA[0][0]); gload16(pA[0][1], b0 + ldsA[0][1]);
    gload16(pA[1][0], b0 + ldsA[1][0]); gload16(pA[1][1], b0 + ldsA[1][1]);
    gload16(pB[0][0], b0 + ldsB[0][0]); gload16(pB[0][1], b0 + ldsB[0][1]);
    gload16(pB[1][0], b0 + ldsB[1][0]); gload16(pB[1][1], b0 + ldsB[1][1]);
    char* b1 = sm + 65536;
    gload16(pB[0][0] + 64, b1 + ldsB[0][0]); gload16(pB[0][1] + 64, b1 + ldsB[0][1]);
    gload16(pB[1][0] + 64, b1 + ldsB[1][0]); gload16(pB[1][1] + 64, b1 + ldsB[1][1]);
  }
  VMW4();
  BARX();

  for (int t = 0; t < nt; ++t) {
    const int cur = t & 1;
    const char* buf = sm + cur * 65536;
    char* nbuf = sm + (cur ^ 1) * 65536;
    char* cbuf = sm + cur * 65536;
    const bool st1 = (t + 1 < nt), st2 = (t + 2 < nt);
    bf16x8 bf0[4], bf1[4];
    bf16x8 a00, a01, a10, a11;

    // phase 0: read A m0,m1 + all B; stage A-h0(t+1); MFMA m0,m1
    a00 = RDA(buf, 0, 0); a01 = RDA(buf, 0, 1);
    a10 = RDA(buf, 1, 0); a11 = RDA(buf, 1, 1);
    #pragma unroll
    for (int n = 0; n < 4; ++n) { bf0[n] = RDB(buf, n, 0); bf1[n] = RDB(buf, n, 1); }
    if (st1) {
      gload16(pA[0][0] + (t + 1) * 64, nbuf + ldsA[0][0]);
      gload16(pA[0][1] + (t + 1) * 64, nbuf + ldsA[0][1]);
    }
    BARX(); LGKM0();
    __builtin_amdgcn_s_setprio(1);
    #pragma unroll
    for (int n = 0; n < 4; ++n) {
      acc[0][n] = MF(a00, bf0[n], acc[0][n]);
      acc[0][n] = MF(a01, bf1[n], acc[0][n]);
      acc[1][n] = MF(a10, bf0[n], acc[1][n]);
      acc[1][n] = MF(a11, bf1[n], acc[1][n]);
    }
    __builtin_amdgcn_s_setprio(0);
    BARX();

    // phase 1: read A m2,m3; stage A-h1(t+1), B-h0(t+2); MFMA m2,m3
    a00 = RDA(buf, 2, 0); a01 = RDA(buf, 2, 1);
    a10 = RDA(buf, 3, 0); a11 = RDA(buf, 3, 1);
    if (st1) {
      gload16(pA[1][0] + (t + 1) * 64, nbuf + ldsA[1][0]);
      gload16(pA[1][1] + (t + 1) * 64, nbuf + ldsA[1][1]);
    }
    if (st2) {
      gload16(pB[0][0] + (t + 2) * 64, cbuf + ldsB[0][0]);
      gload16(pB[0][1] + (t + 2) * 64, cbuf + ldsB[0][1]);
    }
    BARX(); LGKM0();
    __builtin_amdgcn_s_setprio(1);
    #pragma unroll
    for (int n = 0; n < 4; ++n) {
      acc[2][n] = MF(a00, bf0[n], acc[2][n]);
      acc[2][n] = MF(a01, bf1[n], acc[2][n]);
      acc[3][n] = MF(a10, bf0[n], acc[3][n]);
      acc[3][n] = MF(a11, bf1[n], acc[3][n]);
    }
    __builtin_amdgcn_s_setprio(0);
    BARX();

    // phase 2: read A m4,m5; stage B-h1(t+2); MFMA m4,m5
    a00 = RDA(buf, 4, 0); a01 = RDA(buf, 4, 1);
    a10 = RDA(buf, 5, 0); a11 = RDA(buf, 5, 1);
    if (st2) {
      gload16(pB[1][0] + (t + 2) * 64, cbuf + ldsB[1][0]);
      gload16(pB[1][1] + (t + 2) * 64, cbuf + ldsB[1][1]);
    }
    BARX(); LGKM0();
    __builtin_amdgcn_s_setprio(1);
    #pragma unroll
    for (int n = 0; n < 4; ++n) {
      acc[4][n] = MF(a00, bf0[n], acc[4][n]);
      acc[4][n] = MF(a01, bf1[n], acc[4][n]);
      acc[5][n] = MF(a10, bf0[n], acc[5][n]);
      acc[5][n] = MF(a11, bf1[n], acc[5][n]);
    }
    __builtin_amdgcn_s_setprio(0);
    BARX();

    // phase 3: read A m6,m7; counted vmcnt (tile t+1 landed); MFMA m6,m7
    a00 = RDA(buf, 6, 0); a01 = RDA(buf, 6, 1);
    a10 = RDA(buf, 7, 0); a11 = RDA(buf, 7, 1);
    if (st2) { VMW4(); } else if (st1) { VMW0(); }
    BARX(); LGKM0();
    __builtin_amdgcn_s_setprio(1);
    #pragma unroll
    for (int n = 0; n < 4; ++n) {
      acc[6][n] = MF(a00, bf0[n], acc[6][n]);
      acc[6][n] = MF(a01, bf1[n], acc[6][n]);
      acc[7][n] = MF(a10, bf0[n], acc[7][n]);
      acc[7][n] = MF(a11, bf1[n], acc[7][n]);
    }
    __builtin_amdgcn_s_setprio(0);
    BARX();
  }

  if (!wV) {
    const int row0 = bm * 256 + wr * 128 + hi * 4;
    const int col0 = bn * 256 + wc * 64 + fr;
    #pragma unroll
    for (int m = 0; m < 8; ++m)
      #pragma unroll
      for (int n = 0; n < 4; ++n)
        #pragma unroll
        for (int j = 0; j < 4; ++j)
          Yq[(size_t)(row0 + m * 16 + j) * 1024 + (col0 + n * 16)] =
              f2bf(acc[m][n][j]);
  } else {
    // D = Wv.Xv^T: row = e, col = stacked t. Vt[z][e][t], z = bn>>3.
    const int e0 = bm * 256 + wr * 128 + hi * 4;
    const int t0 = (bn & 7) * 256 + wc * 64 + fr;
    const size_t zoff = (size_t)(bn >> 3) * (1024 * 2048);
    #pragma unroll
    for (int m = 0; m < 8; ++m)
      #pragma unroll
      for (int n = 0; n < 4; ++n)
        #pragma unroll
        for (int j = 0; j < 4; ++j)
          Vt[zoff + (size_t)(e0 + m * 16 + j) * 2048 + (t0 + n * 16)] =
              f2bf(acc[m][n][j]);
  }
#undef RDA
#undef RDB
}

// ================================================================ 8-wave 128x128 GEMM
// MODE 0: plain (grid (M/128)*8) — used for Mt.
// MODE 1: causal QK^T, tri-packed, XCD-swizzled, bf16 out (alpha pre-scale).
// MODE 2: causal PV, K clipped to (bm+1)*128, longest-first, f32 out.
template<typename OutT, int MODE>
__global__ __launch_bounds__(512) void gemm_bt8(
    const u16* __restrict__ A, const u16* __restrict__ B, OutT* __restrict__ C,
    int K, int lda, int ldb, int ldc,
    size_t sA, size_t sB, size_t sC, float alpha) {
  int bn, bm, bz = 0;
  int kEnd = K;
  if (MODE == 0) {
    bm = blockIdx.x >> 3;
    bn = blockIdx.x & 7;
  } else if (MODE == 1) {                // grid 544 = 4 * 136 lower-tri tiles
    int h = blockIdx.x;
    int l = (h & 7) * 68 + (h >> 3);
    bz = l / 136;
    int t = l % 136;
    bm = (int)((sqrtf(8.f * (float)t + 1.f) - 1.f) * 0.5f);
    while ((bm + 1) * (bm + 2) / 2 <= t) ++bm;
    while (bm * (bm + 1) / 2 > t) --bm;
    bn = t - bm * (bm + 1) / 2;
  } else {                               // MODE 2, grid 512
    int l = blockIdx.x;
    bm = 15 - (l >> 5);                  // longest kEnd first
    int rest = l & 31;
    bz = rest >> 3;
    bn = rest & 7;
    kEnd = (K < (bm + 1) * 128) ? K : (bm + 1) * 128;
  }
  const u16* Ag = A + sA * bz + (size_t)bm * 128 * lda;
  const u16* Bg = B + sB * bz + (size_t)bn * 128 * ldb;
  OutT* Cg = C + sC * bz;

  __shared__ __align__(16) u16 As[2][128 * 32];
  __shared__ __align__(16) u16 Bs[2][128 * 32];

  const int tid = threadIdx.x;
  const int lane = tid & 63, wv = tid >> 6;   // 8 waves
  const int wr = wv >> 2, wc = wv & 3;        // 2M x 4N
  const int fr = lane & 15, kq = (lane >> 4) * 8;
  const int g4 = (lane >> 4) * 4;

  const int e0 = wv * 512 + lane * 8;
  const int r0 = e0 >> 5, c0 = e0 & 31;
  const u16* a0 = Ag + (size_t)r0 * lda + c0;
  const u16* b0 = Bg + (size_t)r0 * ldb + c0;

  f32x4 acc[4][2] = {};
  const int nt = kEnd / 32;

  gload16(a0, &As[0][wv * 512]);
  gload16(b0, &Bs[0][wv * 512]);
  __syncthreads();

  for (int t = 0; t < nt; ++t) {
    const int cur = t & 1;
    if (t + 1 < nt) {
      const int k0 = (t + 1) * 32;
      gload16(a0 + k0, &As[cur ^ 1][wv * 512]);
      gload16(b0 + k0, &Bs[cur ^ 1][wv * 512]);
    }
    bf16x8 af[4], bfv[2];
    #pragma unroll
    for (int m = 0; m < 4; ++m)
      af[m] = *reinterpret_cast<const bf16x8*>(&As[cur][(wr * 64 + m * 16 + fr) * 32 + kq]);
    #pragma unroll
    for (int n = 0; n < 2; ++n)
      bfv[n] = *reinterpret_cast<const bf16x8*>(&Bs[cur][(wc * 32 + n * 16 + fr) * 32 + kq]);
    #pragma unroll
    for (int m = 0; m < 4; ++m)
      #pragma unroll
      for (int n = 0; n < 2; ++n)
        acc[m][n] = MF(af[m], bfv[n], acc[m][n]);
    __syncthreads();
  }

  const int row0 = bm * 128 + wr * 64 + g4;
  const int col0 = bn * 128 + wc * 32 + fr;
  #pragma unroll
  for (int m = 0; m < 4; ++m)
    #pragma unroll
    for (int n = 0; n < 2; ++n) {
      #pragma unroll
      for (int j = 0; j < 4; ++j) {
        float val = acc[m][n][j] * alpha;
        size_t idx = (size_t)(row0 + m * 16 + j) * ldc + (col0 + n * 16);
        if constexpr (sizeof(OutT) == 2) Cg[idx] = f2bf(val);
        else Cg[idx] = val;
      }
    }
}

// ---------------------------------------------------------------- causal softmax (bf16 in/out, in-place)
__global__ __launch_bounds__(256) void softmax_causal(u16* __restrict__ sc) {
  int r = blockIdx.x;          // 0..8191
  int s = r & 2047;
  u16* row = sc + (size_t)r * 2048;
  int tid = threadIdx.x;
  int t0 = tid * 8;
  u16x8 raw = {0, 0, 0, 0, 0, 0, 0, 0};
  if (t0 <= s) raw = *reinterpret_cast<const u16x8*>(row + t0);
  float v[8];
  float mx = -1e30f;
  #pragma unroll
  for (int j = 0; j < 8; ++j) {
    v[j] = ((t0 + j) <= s) ? bf2f(raw[j]) : -1e30f;
    mx = fmaxf(mx, v[j]);
  }
  #pragma unroll
  for (int o = 32; o; o >>= 1) mx = fmaxf(mx, __shfl_xor(mx, o, 64));
  __shared__ float red[8];
  if ((tid & 63) == 0) red[tid >> 6] = mx;
  __syncthreads();
  mx = fmaxf(fmaxf(red[0], red[1]), fmaxf(red[2], red[3]));
  float p[8];
  float sum = 0.f;
  #pragma unroll
  for (int j = 0; j < 8; ++j) {
    p[j] = ((t0 + j) <= s) ? __expf(v[j] - mx) : 0.f;
    sum += p[j];
  }
  #pragma unroll
  for (int o = 32; o; o >>= 1) sum += __shfl_xor(sum, o, 64);
  if ((tid & 63) == 0) red[4 + (tid >> 6)] = sum;
  __syncthreads();
  sum = red[4] + red[5] + red[6] + red[7];
  float inv = 1.0f / sum;
  u16x8 o8;
  #pragma unroll
  for (int j = 0; j < 8; ++j) o8[j] = f2bf(p[j] * inv);
  if (t0 <= (s | 127))   // PV reads cols < (bm+1)*128 only
    *reinterpret_cast<u16x8*>(row + t0) = o8;
}

// ---------------------------------------------------------------- launcher
extern "C" void kernel_launch(void* const* d_in, const int* in_sizes, int n_in,
                              void* d_out, int out_size, void* d_ws, size_t ws_size,
                              hipStream_t stream) {
  const float* q  = (const float*)d_in[0];
  const float* k  = (const float*)d_in[1];
  const float* v  = (const float*)d_in[2];
  // d_in[3] = attn_mask (causal tril) — handled analytically
  const float* Wq = (const float*)d_in[4];
  const float* Wk = (const float*)d_in[5];
  const float* Wv = (const float*)d_in[6];
  float* out = (float*)d_out;
  char* ws = (char*)d_ws;

  const size_t MB = 1024ull * 1024ull;
  // W-merge: S = Xq.(Wq^T.Wk).Xk^T — K-projection replaced by the Xk cast.
  // sc (32MB) overlays qb slabs 0,1 (Xq,Xv — dead after proj). xk lives
  // through QK. wkT/wqT dead after Mt; wsl dead after proj. proj256 writes
  // Yq and (via swapped-operand MFMA) Vt directly.
  u16* sc   = (u16*)ws;               // 0..32MB  bf16 scores [4][2048][2048]
  u16* qb   = (u16*)ws;               // slabs: 0=Xq, 1=Xv (16MB each)
  u16* xk   = (u16*)(ws + 32 * MB);   // Xk bf16 (16MB, lives through QK)
  u16* wsl  = (u16*)(ws + 48 * MB);   // 4MB: slab0 = Mt, slab1 = Wv_bf
  u16* wkT  = (u16*)(ws + 52 * MB);   // 2MB (dead after Mt)
  u16* wqT  = (u16*)(ws + 54 * MB);   // 2MB (dead after Mt)
  u16* Vt   = (u16*)(ws + 56 * MB);   // 16MB (written by proj, read by PV)
  u16* Yq   = (u16*)(ws + 72 * MB);   // 16MB  -> peak 88MB
  (void)in_sizes; (void)n_in; (void)out_size; (void)ws_size;

  // 1. unified prep: Xq/Xv/Xk casts + WkT/WqT transpose-casts + Wv cast
  prep<<<13056, 256, 0, stream>>>(q, v, k, Wk, Wq, Wv, qb, wkT, wqT,
                                  wsl + 1048576);

  // 2. Mt = WkT . WqT^T = Wk^T.Wq  (Yq = Xq.Mt^T = Xq.Wq^T.Wk)
  gemm_bt8<u16, 0><<<64, 512, 0, stream>>>(
      wkT, wqT, wsl, 1024, 1024, 1024, 1024, 0, 0, 0, 1.0f);

  // 3. 8-phase 256^2 projection, exactly one scheduling round (256 blocks):
  //    Yq = Xq.Mt^T; Vt = Wv.Xv^T (swapped-operand free transpose)
  proj256<<<256, 512, 0, stream>>>(qb, qb + 8388608, wsl, wsl + 1048576,
                                   Yq, Vt);

  // 4. S = Yq . Xk^T (scaled, tri-packed, XCD-swizzled) -> bf16 scores
  gemm_bt8<u16, 1><<<544, 512, 0, stream>>>(
      Yq, xk, sc, 1024, 1024, 1024, 2048,
      (size_t)2048 * 1024, (size_t)2048 * 1024, (size_t)2048 * 2048, 0.03125f);

  // 5. causal softmax, bf16 in/out in place
  softmax_causal<<<8192, 256, 0, stream>>>(sc);

  // 6. PV: P[2048][2048] . Vt[1024][2048]^T -> out f32, longest-first
  gemm_bt8<float, 2><<<512, 512, 0, stream>>>(
      sc, Vt, out, 2048, 2048, 2048, 1024,
      (size_t)2048 * 2048, (size_t)1024 * 2048, (size_t)2048 * 1024, 1.0f);
}

// Round 16
// 156.496 us; speedup vs baseline: 1.2246x; 1.0350x over previous
//
#include <hip/hip_runtime.h>
#include <math.h>

using u16 = unsigned short;
typedef __attribute__((ext_vector_type(8))) __bf16 bf16x8;
typedef __attribute__((ext_vector_type(4))) float f32x4;
typedef __attribute__((ext_vector_type(4))) float f4v;
typedef __attribute__((ext_vector_type(8))) u16 u16x8;

__device__ __forceinline__ u16 f2bf(float f) {
  unsigned u = __float_as_uint(f);
  u += 0x7fffu + ((u >> 16) & 1u);   // round-to-nearest-even
  return (u16)(u >> 16);
}

__device__ __forceinline__ void gload16(const void* g, void* l) {
  __builtin_amdgcn_global_load_lds(
      (const __attribute__((address_space(1))) unsigned int*)g,
      (__attribute__((address_space(3))) unsigned int*)l, 16, 0, 0);
}

__device__ __forceinline__ f32x4 MF(bf16x8 a, bf16x8 b, f32x4 c) {
  return __builtin_amdgcn_mfma_f32_16x16x32_bf16(a, b, c, 0, 0, 0);
}

#define BARX() __builtin_amdgcn_s_barrier()
#define LGKM0() asm volatile("s_waitcnt lgkmcnt(0)" ::: "memory")
#define VMW4() asm volatile("s_waitcnt vmcnt(4)" ::: "memory")
#define VMW0() asm volatile("s_waitcnt vmcnt(0)" ::: "memory")

// ---------------------------------------------------------------- unified prep (one dispatch)
// [0,6144): cast q/v/k f32->bf16, 64B-read/thread (4 loads in flight -> MLP).
// [6144,6656): transpose-cast Wk->WkT (z=0), Wq->WqT (z=1).
// [6656,6912): cast Wv -> wv_bf.   [6912]: zero lbuf[8192].
__global__ __launch_bounds__(256) void prep(
    const float* __restrict__ q, const float* __restrict__ v,
    const float* __restrict__ k, const float* __restrict__ Wk,
    const float* __restrict__ Wq, const float* __restrict__ Wv,
    u16* __restrict__ qb, u16* __restrict__ wkT, u16* __restrict__ wqT,
    u16* __restrict__ wv_bf, float* __restrict__ lbuf) {
  __shared__ float t[64][65];
  int b = blockIdx.x;
  if (b < 6144) {
    int z = b >> 11;
    int bb = b & 2047;
    const float* in = (z == 0) ? q : (z == 1) ? v : k;
    size_t i = ((size_t)bb * 256 + threadIdx.x) * 16;
    f4v a0 = *reinterpret_cast<const f4v*>(in + i);
    f4v a1 = *reinterpret_cast<const f4v*>(in + i + 4);
    f4v a2 = *reinterpret_cast<const f4v*>(in + i + 8);
    f4v a3 = *reinterpret_cast<const f4v*>(in + i + 12);
    u16x8 r0, r1;
    r0[0] = f2bf(a0[0]); r0[1] = f2bf(a0[1]); r0[2] = f2bf(a0[2]); r0[3] = f2bf(a0[3]);
    r0[4] = f2bf(a1[0]); r0[5] = f2bf(a1[1]); r0[6] = f2bf(a1[2]); r0[7] = f2bf(a1[3]);
    r1[0] = f2bf(a2[0]); r1[1] = f2bf(a2[1]); r1[2] = f2bf(a2[2]); r1[3] = f2bf(a2[3]);
    r1[4] = f2bf(a3[0]); r1[5] = f2bf(a3[1]); r1[6] = f2bf(a3[2]); r1[7] = f2bf(a3[3]);
    u16* o = qb + (size_t)z * 8388608 + i;
    *reinterpret_cast<u16x8*>(o) = r0;
    *reinterpret_cast<u16x8*>(o + 8) = r1;
  } else if (b < 6656) {
    int c = b - 6144;
    int z = c >> 8, idx = c & 255;
    const float* I = z ? Wq : Wk;
    u16* O = z ? wqT : wkT;
    int c0 = (idx & 15) * 64, r0 = (idx >> 4) * 64;
    int tx = threadIdx.x & 63, ty = threadIdx.x >> 6;
    #pragma unroll
    for (int i = 0; i < 64; i += 4)
      t[ty + i][tx] = I[(size_t)(r0 + ty + i) * 1024 + c0 + tx];
    __syncthreads();
    #pragma unroll
    for (int i = 0; i < 64; i += 4)
      O[(size_t)(c0 + ty + i) * 1024 + r0 + tx] = f2bf(t[tx][ty + i]);
  } else if (b < 6912) {
    int bb = b - 6656;                  // 0..255
    size_t i = (size_t)bb * 4096 + threadIdx.x * 16;
    #pragma unroll
    for (int h = 0; h < 2; ++h) {
      f4v a = *reinterpret_cast<const f4v*>(Wv + i + h * 8);
      f4v c = *reinterpret_cast<const f4v*>(Wv + i + h * 8 + 4);
      u16x8 r;
      r[0] = f2bf(a[0]); r[1] = f2bf(a[1]); r[2] = f2bf(a[2]); r[3] = f2bf(a[3]);
      r[4] = f2bf(c[0]); r[5] = f2bf(c[1]); r[6] = f2bf(c[2]); r[7] = f2bf(c[3]);
      *reinterpret_cast<u16x8*>(wv_bf + i + h * 8) = r;
    }
  } else {
    f4v z4 = {0.f, 0.f, 0.f, 0.f};
    #pragma unroll
    for (int j = 0; j < 8; ++j)
      *reinterpret_cast<f4v*>(&lbuf[threadIdx.x * 32 + j * 4]) = z4;
  }
}

// ================================================================ 256x256 8-phase projection
// (unchanged from R15 — verified) Grid 256, 8 waves, K=1024, LDS 128KB dbuf,
// XOR swizzle, counted vmcnt. Tiles [0,128): Yq = Xq.Mt^T. Tiles [128,256):
// D = Wv.Xv^T written as Vt (swapped-operand free transpose).
__global__ __launch_bounds__(512, 1) void proj256(
    const u16* __restrict__ Xq, const u16* __restrict__ Xv,
    const u16* __restrict__ Mt, const u16* __restrict__ Wv,
    u16* __restrict__ Yq, u16* __restrict__ Vt) {
  int h = blockIdx.x;
  int l = (h & 7) * 32 + (h >> 3);
  const bool wV = l >= 128;
  int li = l & 127;
  int bm, bn;
  const u16 *Ag, *Bg;
  if (!wV) {
    bm = li >> 2; bn = li & 3;
    Ag = Xq + (size_t)bm * 256 * 1024;
    Bg = Mt + (size_t)bn * 256 * 1024;
  } else {
    bm = li & 3; bn = li >> 2;
    Ag = Wv + (size_t)bm * 256 * 1024;
    Bg = Xv + (size_t)bn * 256 * 1024;
  }

  __shared__ __align__(16) char sm[131072];

  const int tid = threadIdx.x;
  const int lane = tid & 63, wv = tid >> 6;
  const int wr = wv >> 2, wc = wv & 3;
  const int fr = lane & 15, hi = lane >> 4, fr7 = lane & 7;
  const int l3 = lane >> 3;
  const int colsw = ((lane & 7) ^ l3) * 8;
  const int lnx16 = lane * 16;

  const u16 *pA[2][2], *pB[2][2];
  int ldsA[2][2], ldsB[2][2];
  #pragma unroll
  for (int hh = 0; hh < 2; ++hh)
    #pragma unroll
    for (int j = 0; j < 2; ++j) {
      int row = hh * 128 + wv * 8 + j * 64 + l3;
      pA[hh][j] = Ag + (size_t)row * 1024 + colsw;
      pB[hh][j] = Bg + (size_t)row * 1024 + colsw;
      ldsA[hh][j] = hh * 16384 + (wv + j * 8) * 1024 + lnx16;
      ldsB[hh][j] = 32768 + ldsA[hh][j];
    }

  const int aBase = wr * 16384 + fr * 128;
  const int bBase = 32768 + (wc >> 1) * 16384 + ((wc & 1) * 64 + fr) * 128;
  const int sl0 = (hi ^ fr7) << 4;
  const int sl1 = ((4 + hi) ^ fr7) << 4;

#define RDA(buf, m, kk) (*(const bf16x8*)((buf) + aBase + (m) * 2048 + ((kk) ? sl1 : sl0)))
#define RDB(buf, n, kk) (*(const bf16x8*)((buf) + bBase + (n) * 2048 + ((kk) ? sl1 : sl0)))

  f32x4 acc[8][4] = {};
  const int nt = 16;

  {
    char* b0 = sm;
    gload16(pA[0][0], b0 + ldsA[0][0]); gload16(pA[0][1], b0 + ldsA[0][1]);
    gload16(pA[1][0], b0 + ldsA[1][0]); gload16(pA[1][1], b0 + ldsA[1][1]);
    gload16(pB[0][0], b0 + ldsB[0][0]); gload16(pB[0][1], b0 + ldsB[0][1]);
    gload16(pB[1][0], b0 + ldsB[1][0]); gload16(pB[1][1], b0 + ldsB[1][1]);
    char* b1 = sm + 65536;
    gload16(pB[0][0] + 64, b1 + ldsB[0][0]); gload16(pB[0][1] + 64, b1 + ldsB[0][1]);
    gload16(pB[1][0] + 64, b1 + ldsB[1][0]); gload16(pB[1][1] + 64, b1 + ldsB[1][1]);
  }
  VMW4();
  BARX();

  for (int t = 0; t < nt; ++t) {
    const int cur = t & 1;
    const char* buf = sm + cur * 65536;
    char* nbuf = sm + (cur ^ 1) * 65536;
    char* cbuf = sm + cur * 65536;
    const bool st1 = (t + 1 < nt), st2 = (t + 2 < nt);
    bf16x8 bf0[4], bf1[4];
    bf16x8 a00, a01, a10, a11;

    a00 = RDA(buf, 0, 0); a01 = RDA(buf, 0, 1);
    a10 = RDA(buf, 1, 0); a11 = RDA(buf, 1, 1);
    #pragma unroll
    for (int n = 0; n < 4; ++n) { bf0[n] = RDB(buf, n, 0); bf1[n] = RDB(buf, n, 1); }
    if (st1) {
      gload16(pA[0][0] + (t + 1) * 64, nbuf + ldsA[0][0]);
      gload16(pA[0][1] + (t + 1) * 64, nbuf + ldsA[0][1]);
    }
    BARX(); LGKM0();
    __builtin_amdgcn_s_setprio(1);
    #pragma unroll
    for (int n = 0; n < 4; ++n) {
      acc[0][n] = MF(a00, bf0[n], acc[0][n]);
      acc[0][n] = MF(a01, bf1[n], acc[0][n]);
      acc[1][n] = MF(a10, bf0[n], acc[1][n]);
      acc[1][n] = MF(a11, bf1[n], acc[1][n]);
    }
    __builtin_amdgcn_s_setprio(0);
    BARX();

    a00 = RDA(buf, 2, 0); a01 = RDA(buf, 2, 1);
    a10 = RDA(buf, 3, 0); a11 = RDA(buf, 3, 1);
    if (st1) {
      gload16(pA[1][0] + (t + 1) * 64, nbuf + ldsA[1][0]);
      gload16(pA[1][1] + (t + 1) * 64, nbuf + ldsA[1][1]);
    }
    if (st2) {
      gload16(pB[0][0] + (t + 2) * 64, cbuf + ldsB[0][0]);
      gload16(pB[0][1] + (t + 2) * 64, cbuf + ldsB[0][1]);
    }
    BARX(); LGKM0();
    __builtin_amdgcn_s_setprio(1);
    #pragma unroll
    for (int n = 0; n < 4; ++n) {
      acc[2][n] = MF(a00, bf0[n], acc[2][n]);
      acc[2][n] = MF(a01, bf1[n], acc[2][n]);
      acc[3][n] = MF(a10, bf0[n], acc[3][n]);
      acc[3][n] = MF(a11, bf1[n], acc[3][n]);
    }
    __builtin_amdgcn_s_setprio(0);
    BARX();

    a00 = RDA(buf, 4, 0); a01 = RDA(buf, 4, 1);
    a10 = RDA(buf, 5, 0); a11 = RDA(buf, 5, 1);
    if (st2) {
      gload16(pB[1][0] + (t + 2) * 64, cbuf + ldsB[1][0]);
      gload16(pB[1][1] + (t + 2) * 64, cbuf + ldsB[1][1]);
    }
    BARX(); LGKM0();
    __builtin_amdgcn_s_setprio(1);
    #pragma unroll
    for (int n = 0; n < 4; ++n) {
      acc[4][n] = MF(a00, bf0[n], acc[4][n]);
      acc[4][n] = MF(a01, bf1[n], acc[4][n]);
      acc[5][n] = MF(a10, bf0[n], acc[5][n]);
      acc[5][n] = MF(a11, bf1[n], acc[5][n]);
    }
    __builtin_amdgcn_s_setprio(0);
    BARX();

    a00 = RDA(buf, 6, 0); a01 = RDA(buf, 6, 1);
    a10 = RDA(buf, 7, 0); a11 = RDA(buf, 7, 1);
    if (st2) { VMW4(); } else if (st1) { VMW0(); }
    BARX(); LGKM0();
    __builtin_amdgcn_s_setprio(1);
    #pragma unroll
    for (int n = 0; n < 4; ++n) {
      acc[6][n] = MF(a00, bf0[n], acc[6][n]);
      acc[6][n] = MF(a01, bf1[n], acc[6][n]);
      acc[7][n] = MF(a10, bf0[n], acc[7][n]);
      acc[7][n] = MF(a11, bf1[n], acc[7][n]);
    }
    __builtin_amdgcn_s_setprio(0);
    BARX();
  }

  if (!wV) {
    const int row0 = bm * 256 + wr * 128 + hi * 4;
    const int col0 = bn * 256 + wc * 64 + fr;
    #pragma unroll
    for (int m = 0; m < 8; ++m)
      #pragma unroll
      for (int n = 0; n < 4; ++n)
        #pragma unroll
        for (int j = 0; j < 4; ++j)
          Yq[(size_t)(row0 + m * 16 + j) * 1024 + (col0 + n * 16)] =
              f2bf(acc[m][n][j]);
  } else {
    const int e0 = bm * 256 + wr * 128 + hi * 4;
    const int t0 = (bn & 7) * 256 + wc * 64 + fr;
    const size_t zoff = (size_t)(bn >> 3) * (1024 * 2048);
    #pragma unroll
    for (int m = 0; m < 8; ++m)
      #pragma unroll
      for (int n = 0; n < 4; ++n)
        #pragma unroll
        for (int j = 0; j < 4; ++j)
          Vt[zoff + (size_t)(e0 + m * 16 + j) * 2048 + (t0 + n * 16)] =
              f2bf(acc[m][n][j]);
  }
#undef RDA
#undef RDB
}

// ================================================================ 8-wave 128x128 GEMM
// MODE 0: plain — used for Mt.
// MODE 1: causal QK^T, tri-packed, XCD-swizzled: writes P = exp(s*alpha) bf16
//         (masked cols -> 0) and atomicAdds per-row l = Σexp into lbuf.
// MODE 2: causal PV on pre-exp'd P: standard MFMA loop; epilogue scales 1/l.
template<typename OutT, int MODE>
__global__ __launch_bounds__(512) void gemm_bt8(
    const u16* __restrict__ A, const u16* __restrict__ B, OutT* __restrict__ C,
    int K, int lda, int ldb, int ldc,
    size_t sA, size_t sB, size_t sC, float alpha, float* __restrict__ lbuf) {
  int bn, bm, bz = 0;
  int kEnd = K;
  if (MODE == 0) {
    bm = blockIdx.x >> 3;
    bn = blockIdx.x & 7;
  } else if (MODE == 1) {                // grid 544 = 4 * 136 lower-tri tiles
    int h = blockIdx.x;
    int l = (h & 7) * 68 + (h >> 3);
    bz = l / 136;
    int t = l % 136;
    bm = (int)((sqrtf(8.f * (float)t + 1.f) - 1.f) * 0.5f);
    while ((bm + 1) * (bm + 2) / 2 <= t) ++bm;
    while (bm * (bm + 1) / 2 > t) --bm;
    bn = t - bm * (bm + 1) / 2;
  } else {                               // MODE 2, grid 512
    int l = blockIdx.x;
    bm = 15 - (l >> 5);                  // longest kEnd first
    int rest = l & 31;
    bz = rest >> 3;
    bn = rest & 7;
    kEnd = (K < (bm + 1) * 128) ? K : (bm + 1) * 128;
  }
  const u16* Ag = A + sA * bz + (size_t)bm * 128 * lda;
  const u16* Bg = B + sB * bz + (size_t)bn * 128 * ldb;
  OutT* Cg = C + sC * bz;

  __shared__ __align__(16) u16 As[2][128 * 32];
  __shared__ __align__(16) u16 Bs[2][128 * 32];

  const int tid = threadIdx.x;
  const int lane = tid & 63, wv = tid >> 6;   // 8 waves
  const int wr = wv >> 2, wc = wv & 3;        // 2M x 4N
  const int fr = lane & 15, kq = (lane >> 4) * 8;
  const int g4 = (lane >> 4) * 4;

  const int e0 = wv * 512 + lane * 8;
  const int r0 = e0 >> 5, c0 = e0 & 31;
  const u16* a0 = Ag + (size_t)r0 * lda + c0;
  const u16* b0 = Bg + (size_t)r0 * ldb + c0;

  f32x4 acc[4][2] = {};
  const int nt = kEnd / 32;

  gload16(a0, &As[0][wv * 512]);
  gload16(b0, &Bs[0][wv * 512]);
  __syncthreads();

  for (int t = 0; t < nt; ++t) {
    const int cur = t & 1;
    if (t + 1 < nt) {
      const int k0 = (t + 1) * 32;
      gload16(a0 + k0, &As[cur ^ 1][wv * 512]);
      gload16(b0 + k0, &Bs[cur ^ 1][wv * 512]);
    }
    bf16x8 af[4], bfv[2];
    #pragma unroll
    for (int m = 0; m < 4; ++m)
      af[m] = *reinterpret_cast<const bf16x8*>(&As[cur][(wr * 64 + m * 16 + fr) * 32 + kq]);
    #pragma unroll
    for (int n = 0; n < 2; ++n)
      bfv[n] = *reinterpret_cast<const bf16x8*>(&Bs[cur][(wc * 32 + n * 16 + fr) * 32 + kq]);
    #pragma unroll
    for (int m = 0; m < 4; ++m)
      #pragma unroll
      for (int n = 0; n < 2; ++n)
        acc[m][n] = MF(af[m], bfv[n], acc[m][n]);
    __syncthreads();
  }

  if constexpr (MODE == 1) {
    // write P = exp(s) bf16 (masked -> 0); per-row Σexp -> lbuf atomics
    float psum[4][4];
    #pragma unroll
    for (int m = 0; m < 4; ++m)
      #pragma unroll
      for (int j = 0; j < 4; ++j) {
        int tr = wr * 64 + g4 + m * 16 + j;
        float rs = 0.f;
        #pragma unroll
        for (int n = 0; n < 2; ++n) {
          int tc = wc * 32 + fr + n * 16;
          float p = 0.f;
          if (!(bm == bn && tc > tr)) p = __expf(acc[m][n][j] * alpha);
          Cg[(size_t)(bm * 128 + tr) * ldc + (bn * 128 + tc)] = f2bf(p);
          rs += p;
        }
        psum[m][j] = rs;
      }
    #pragma unroll
    for (int o = 1; o < 16; o <<= 1)
      #pragma unroll
      for (int m = 0; m < 4; ++m)
        #pragma unroll
        for (int j = 0; j < 4; ++j)
          psum[m][j] += __shfl_xor(psum[m][j], o, 64);
    float* lsum = (float*)As;          // [4 wc][128 rows]
    if (fr == 0)
      #pragma unroll
      for (int m = 0; m < 4; ++m)
        #pragma unroll
        for (int j = 0; j < 4; ++j)
          lsum[wc * 128 + wr * 64 + g4 + m * 16 + j] = psum[m][j];
    __syncthreads();
    if (tid < 128) {
      float s = lsum[tid] + lsum[128 + tid] + lsum[256 + tid] + lsum[384 + tid];
      atomicAdd(&lbuf[(size_t)bz * 2048 + bm * 128 + tid], s);
    }
    return;
  }

  float il[4][4];
  if constexpr (MODE == 2) {
    #pragma unroll
    for (int m = 0; m < 4; ++m)
      #pragma unroll
      for (int j = 0; j < 4; ++j)
        il[m][j] = 1.0f / lbuf[(size_t)bz * 2048 + bm * 128 + wr * 64 + g4 + m * 16 + j];
  }

  const int row0 = bm * 128 + wr * 64 + g4;
  const int col0 = bn * 128 + wc * 32 + fr;
  #pragma unroll
  for (int m = 0; m < 4; ++m)
    #pragma unroll
    for (int n = 0; n < 2; ++n) {
      #pragma unroll
      for (int j = 0; j < 4; ++j) {
        float val;
        if constexpr (MODE == 2) val = acc[m][n][j] * il[m][j];
        else val = acc[m][n][j] * alpha;
        size_t idx = (size_t)(row0 + m * 16 + j) * ldc + (col0 + n * 16);
        if constexpr (sizeof(OutT) == 2) Cg[idx] = f2bf(val);
        else Cg[idx] = val;
      }
    }
}

// ---------------------------------------------------------------- launcher
extern "C" void kernel_launch(void* const* d_in, const int* in_sizes, int n_in,
                              void* d_out, int out_size, void* d_ws, size_t ws_size,
                              hipStream_t stream) {
  const float* q  = (const float*)d_in[0];
  const float* k  = (const float*)d_in[1];
  const float* v  = (const float*)d_in[2];
  // d_in[3] = attn_mask (causal tril) — handled analytically
  const float* Wq = (const float*)d_in[4];
  const float* Wk = (const float*)d_in[5];
  const float* Wv = (const float*)d_in[6];
  float* out = (float*)d_out;
  char* ws = (char*)d_ws;

  const size_t MB = 1024ull * 1024ull;
  // W-merge: S = Xq.(Wq^T.Wk).Xk^T. Softmax-free: QK writes P=exp(s) + row
  // sums l (atomics); PV scales by 1/l. sc (32MB P) overlays qb slabs 0,1.
  u16* sc   = (u16*)ws;               // 0..32MB  bf16 P [4][2048][2048]
  u16* qb   = (u16*)ws;               // slabs: 0=Xq, 1=Xv (16MB each)
  u16* xk   = (u16*)(ws + 32 * MB);   // Xk bf16 (16MB, lives through QK)
  u16* wsl  = (u16*)(ws + 48 * MB);   // 4MB: slab0 = Mt, slab1 = Wv_bf
  u16* wkT  = (u16*)(ws + 52 * MB);   // 2MB (dead after Mt)
  u16* wqT  = (u16*)(ws + 54 * MB);   // 2MB (dead after Mt)
  u16* Vt   = (u16*)(ws + 56 * MB);   // 16MB (written by proj, read by PV)
  u16* Yq   = (u16*)(ws + 72 * MB);   // 16MB
  float* lb = (float*)(ws + 88 * MB); // 32KB row sums [4][2048]
  (void)in_sizes; (void)n_in; (void)out_size; (void)ws_size;

  // 1. unified prep: X casts (64B/thread) + weight prep + lbuf zero
  prep<<<6913, 256, 0, stream>>>(q, v, k, Wk, Wq, Wv, qb, wkT, wqT,
                                 wsl + 1048576, lb);

  // 2. Mt = WkT . WqT^T = Wk^T.Wq
  gemm_bt8<u16, 0><<<64, 512, 0, stream>>>(
      wkT, wqT, wsl, 1024, 1024, 1024, 1024, 0, 0, 0, 1.0f, nullptr);

  // 3. 8-phase 256^2 projection (one full round): Yq = Xq.Mt^T; Vt = Wv.Xv^T
  proj256<<<256, 512, 0, stream>>>(qb, qb + 8388608, wsl, wsl + 1048576,
                                   Yq, Vt);

  // 4. QK: P = exp(Yq.Xk^T * alpha) bf16 + row sums (tri-packed, swizzled)
  gemm_bt8<u16, 1><<<544, 512, 0, stream>>>(
      Yq, xk, sc, 1024, 1024, 1024, 2048,
      (size_t)2048 * 1024, (size_t)2048 * 1024, (size_t)2048 * 2048, 0.03125f,
      lb);

  // 5. PV: P . Vt^T scaled by 1/l -> out f32, longest-first
  gemm_bt8<float, 2><<<512, 512, 0, stream>>>(
      sc, Vt, out, 2048, 2048, 2048, 1024,
      (size_t)2048 * 2048, (size_t)1024 * 2048, (size_t)2048 * 1024, 1.0f,
      lb);
}